// Round 2
// baseline (33.962 us; speedup 1.0000x reference)
//
#include <hip/hip_runtime.h>

// out[b,h] = (X X^T) X == X (X^T X) per head; X = x[b,h] : [2048 x 64] fp32.
// B*H = 32 heads. G = X^T X (64x64) via 32 partials -> fixed-order reduce -> out = X G.

#define TDIM 2048
#define DDIM 64
#define NHEADS 32
#define NCH 32          // 64-row chunks per head

// Async global->LDS DMA, 16 B per lane. lptr must be the WAVE-UNIFORM base;
// HW scatters lane l to lptr + l*16. gptr is per-lane.
__device__ __forceinline__ void async_copy16(const float* g, float* l) {
    __builtin_amdgcn_global_load_lds(
        (const __attribute__((address_space(1))) void*)g,
        (__attribute__((address_space(3))) void*)l, 16, 0, 0);
}

// ---------------------------------------------------------------------------
// Kernel 1: partial Gram. grid = (NCH, NHEADS), block = 256 (4 waves).
// Block (c,h): stages rows [64c, 64c+64) of head h into LDS (linear 64x64,
// DMA'd), then each thread accumulates a 4x4 tile of sum_t x[t][i]*x[t][j].
// Unpadded layout: xs[t][j0] b128 reads are exactly 2-way bank-aliased (free),
// xs[t][i0] is a 16-lane broadcast.
// ---------------------------------------------------------------------------
__global__ __launch_bounds__(256) void gram_partial(const float* __restrict__ x,
                                                    float* __restrict__ part) {
    const int head  = blockIdx.y;
    const int chunk = blockIdx.x;
    const int tid   = threadIdx.x;
    const int lane  = tid & 63;
    const int wv    = tid >> 6;

    __shared__ float xs[64][64];

    const float* xh = x + ((size_t)head * TDIM + (size_t)chunk * 64) * DDIM;

    // Wave wv DMAs bytes [wv*4096, (wv+1)*4096) of the 16 KB tile.
    const float* gsrc = xh + wv * 1024 + lane * 4;   // lane*16 B
    float* ldst = &xs[0][0] + wv * 1024;             // wave-uniform
#pragma unroll
    for (int it = 0; it < 4; ++it)
        async_copy16(gsrc + it * 256, ldst + it * 256);
    __syncthreads();

    const int i0 = (tid >> 4) << 2;
    const int j0 = (tid & 15) << 2;

    float acc[4][4];
#pragma unroll
    for (int a = 0; a < 4; ++a)
#pragma unroll
        for (int b = 0; b < 4; ++b) acc[a][b] = 0.f;

#pragma unroll 8
    for (int t = 0; t < 64; ++t) {
        const float4 av = *reinterpret_cast<const float4*>(&xs[t][i0]);
        const float4 bv = *reinterpret_cast<const float4*>(&xs[t][j0]);
        const float aa[4] = {av.x, av.y, av.z, av.w};
        const float bb[4] = {bv.x, bv.y, bv.z, bv.w};
#pragma unroll
        for (int a = 0; a < 4; ++a)
#pragma unroll
            for (int b = 0; b < 4; ++b) acc[a][b] += aa[a] * bb[b];
    }

    float* p = part + ((size_t)head * NCH + chunk) * 4096;
#pragma unroll
    for (int a = 0; a < 4; ++a)
        *reinterpret_cast<float4*>(p + (i0 + a) * 64 + j0) =
            make_float4(acc[a][0], acc[a][1], acc[a][2], acc[a][3]);
}

// ---------------------------------------------------------------------------
// Kernel 2: fixed-order reduction, float4 per thread.
// 32 heads * 1024 float4 = 32768 threads = 128 blocks x 256.
// ---------------------------------------------------------------------------
__global__ __launch_bounds__(256) void gram_reduce(const float* __restrict__ part,
                                                   float* __restrict__ G) {
    const int gid = blockIdx.x * 256 + threadIdx.x;  // 0..32767
    const int h  = gid >> 10;
    const int e4 = (gid & 1023) << 2;
    const float* p = part + (size_t)h * NCH * 4096 + e4;
    float4 s = make_float4(0.f, 0.f, 0.f, 0.f);
#pragma unroll 8
    for (int c = 0; c < NCH; ++c) {
        const float4 v = *reinterpret_cast<const float4*>(p + (size_t)c * 4096);
        s.x += v.x; s.y += v.y; s.z += v.z; s.w += v.w;
    }
    *reinterpret_cast<float4*>(G + (size_t)h * 4096 + e4) = s;
}

// ---------------------------------------------------------------------------
// Kernel 3: out = X * G. grid = (TDIM/64, NHEADS), block = 256.
// DMA-stages G (16 KB) and a 64-row X tile (16 KB) into LDS concurrently.
// ---------------------------------------------------------------------------
__global__ __launch_bounds__(256) void xg_kernel(const float* __restrict__ x,
                                                 const float* __restrict__ G,
                                                 float* __restrict__ out) {
    const int head = blockIdx.y;
    const int row0 = blockIdx.x * 64;
    const int tid  = threadIdx.x;
    const int lane = tid & 63;
    const int wv   = tid >> 6;

    __shared__ float Gs[4096];
    __shared__ float xs[64][64];

    const float* xh = x + ((size_t)head * TDIM + row0) * DDIM;
    const float* Gh = G + (size_t)head * 4096;

    const float* gsrcX = xh + wv * 1024 + lane * 4;
    const float* gsrcG = Gh + wv * 1024 + lane * 4;
    float* ldX = &xs[0][0] + wv * 1024;
    float* ldG = Gs + wv * 1024;
#pragma unroll
    for (int it = 0; it < 4; ++it) {
        async_copy16(gsrcX + it * 256, ldX + it * 256);
        async_copy16(gsrcG + it * 256, ldG + it * 256);
    }
    __syncthreads();

    const int r0 = (tid >> 4) << 2;
    const int d0 = (tid & 15) << 2;

    float acc[4][4];
#pragma unroll
    for (int a = 0; a < 4; ++a)
#pragma unroll
        for (int b = 0; b < 4; ++b) acc[a][b] = 0.f;

#pragma unroll 4
    for (int i = 0; i < 64; i += 4) {
        float4 g[4];
        float4 xv[4];
#pragma unroll
        for (int ii = 0; ii < 4; ++ii)
            g[ii] = *reinterpret_cast<const float4*>(&Gs[(i + ii) * 64 + d0]);
#pragma unroll
        for (int k = 0; k < 4; ++k)
            xv[k] = *reinterpret_cast<const float4*>(&xs[r0 + k][i]);
#pragma unroll
        for (int k = 0; k < 4; ++k) {
            const float xk[4] = {xv[k].x, xv[k].y, xv[k].z, xv[k].w};
#pragma unroll
            for (int ii = 0; ii < 4; ++ii) {
                acc[k][0] += xk[ii] * g[ii].x;
                acc[k][1] += xk[ii] * g[ii].y;
                acc[k][2] += xk[ii] * g[ii].z;
                acc[k][3] += xk[ii] * g[ii].w;
            }
        }
    }

    float* oh = out + ((size_t)head * TDIM + row0) * DDIM;
#pragma unroll
    for (int k = 0; k < 4; ++k)
        *reinterpret_cast<float4*>(oh + (size_t)(r0 + k) * DDIM + d0) =
            make_float4(acc[k][0], acc[k][1], acc[k][2], acc[k][3]);
}

extern "C" void kernel_launch(void* const* d_in, const int* in_sizes, int n_in,
                              void* d_out, int out_size, void* d_ws, size_t ws_size,
                              hipStream_t stream) {
    const float* x = (const float*)d_in[0];
    float* out = (float*)d_out;
    float* ws  = (float*)d_ws;

    // ws layout: [ part: NHEADS*NCH*4096 ][ G: NHEADS*4096 ] floats = 17.3 MB.
    float* part = ws;
    float* G    = ws + (size_t)NHEADS * NCH * 4096;

    dim3 g1(NCH, NHEADS);
    gram_partial<<<g1, 256, 0, stream>>>(x, part);

    gram_reduce<<<(NHEADS * 1024) / 256, 256, 0, stream>>>(part, G);

    dim3 g2(TDIM / 64, NHEADS);
    xg_kernel<<<g2, 256, 0, stream>>>(x, G, out);
}